// Round 6
// baseline (690.509 us; speedup 1.0000x reference)
//
#include <hip/hip_runtime.h>
#include <math.h>
#include <stdint.h>

#define NROWS 48000
#define KDIM 512
#define NE 320
#define GE 640
#define DDIM 384
#define ODIM 768
#define CB_OFF 36864000ul
#define SC_OFF 67584000ul
#define MARGIN 4e-3f

using f16x8 = __attribute__((ext_vector_type(8))) _Float16;
using f32x4 = __attribute__((ext_vector_type(4))) float;

#define GLD16(gp, lp)                                                          \
    __builtin_amdgcn_global_load_lds(                                          \
        (const __attribute__((address_space(1))) uint32_t*)(gp),               \
        (__attribute__((address_space(3))) uint32_t*)(lp), 16, 0, 0)

// ---------------- split f32 -> f16 hi + f16 lo (W only, 1.3 MB) -----------
__global__ __launch_bounds__(256) void split16(const float* __restrict__ src,
                                               _Float16* __restrict__ hi,
                                               _Float16* __restrict__ lo,
                                               int n8)
{
    int i = blockIdx.x * 256 + threadIdx.x;
    if (i >= n8) return;
    float4 v0 = *((const float4*)src + 2 * (size_t)i);
    float4 v1 = *((const float4*)src + 2 * (size_t)i + 1);
    float x[8] = {v0.x, v0.y, v0.z, v0.w, v1.x, v1.y, v1.z, v1.w};
    f16x8 h, l;
    #pragma unroll
    for (int k = 0; k < 8; ++k) {
        _Float16 hh = (_Float16)x[k];
        h[k] = hh;
        l[k] = (_Float16)(x[k] - (float)hh);
    }
    *(f16x8*)(hi + (size_t)i * 8) = h;
    *(f16x8*)(lo + (size_t)i * 8) = l;
}

// ---------------- helpers -------------------------------------------------
__device__ __forceinline__ bool better(float a, int ia, float b, int ib) {
    return (a > b) || (a == b && ia < ib);
}

// top-2 across a 32-lane half; v[i] corresponds to e = il + 32*i
__device__ __forceinline__ void top2_half(const float* v, int il,
                                          float& v1, int& i1, float& v2, int& i2)
{
    v1 = -3.4e38f; i1 = 0x7fffffff;
    v2 = -3.4e38f; i2 = 0x7fffffff;
    #pragma unroll
    for (int i = 0; i < 10; ++i) {
        int e = il + 32 * i;
        float x = v[i];
        if (better(x, e, v1, i1)) { v2 = v1; i2 = i1; v1 = x; i1 = e; }
        else if (better(x, e, v2, i2)) { v2 = x; i2 = e; }
    }
    #pragma unroll
    for (int m = 1; m <= 16; m <<= 1) {
        float ov1 = __shfl_xor(v1, m); int oi1 = __shfl_xor(i1, m);
        float ov2 = __shfl_xor(v2, m); int oi2 = __shfl_xor(i2, m);
        float lv; int li;
        if (better(ov1, oi1, v1, i1)) { lv = v1; li = i1; v1 = ov1; i1 = oi1; }
        else { lv = ov1; li = oi1; }
        if (better(lv, li, v2, i2)) { v2 = lv; i2 = li; }
        if (better(ov2, oi2, v2, i2)) { v2 = ov2; i2 = oi2; }
    }
}

// fp64 re-resolution of a near-tied argmax; runs in a 32-lane half
__device__ int resolve2(const float* __restrict__ X, const float* __restrict__ W,
                        const float* __restrict__ bvec, const float* __restrict__ Urow,
                        int n, int h, int c1, int c2, bool gum, int il)
{
    const float* xr = X + (size_t)n * KDIM;
    const float* w1 = W + (size_t)(h * NE + c1) * KDIM;
    const float* w2 = W + (size_t)(h * NE + c2) * KDIM;
    double d1 = 0.0, d2 = 0.0;
    #pragma unroll
    for (int j = 0; j < 16; ++j) {
        int k = il + 32 * j;
        double xv = (double)xr[k];
        d1 += xv * (double)w1[k];
        d2 += xv * (double)w2[k];
    }
    #pragma unroll
    for (int m = 1; m <= 16; m <<= 1) {
        d1 += __shfl_xor(d1, m);
        d2 += __shfl_xor(d2, m);
    }
    d1 += (double)bvec[h * NE + c1];
    d2 += (double)bvec[h * NE + c2];
    if (gum) {
        d1 += -log(-log((double)Urow[c1] + 1e-10) + 1e-10);
        d2 += -log(-log((double)Urow[c2] + 1e-10) + 1e-10);
    }
    return (d2 > d1 || (d2 == d1 && c2 < c1)) ? c2 : c1;
}

// ---------------- fused GEMM + chunk-ownership epilogue -------------------
// GEMM part identical to round-5 gemm_cvt (128x128 tile, 3-pass split-f16).
// After C-write, each of the 5 column-blocks of a 128-row panel bumps the
// panel's 4 chunk counters (agent-scope ACQ_REL); the 5th arrival owns the
// 32-row chunk and runs the epilogue for it (logits still L2/L3-hot).
__global__ __launch_bounds__(256) void gemm_fused(
    const float* __restrict__ X, const float* __restrict__ Wf,
    const _Float16* __restrict__ Wh, const _Float16* __restrict__ Wl,
    const float* __restrict__ bvec, const float* __restrict__ entries,
    const float* __restrict__ gumbel, float* __restrict__ out,
    float* __restrict__ gavgp, unsigned int* __restrict__ gcnt,
    unsigned int* __restrict__ panelcnt)
{
    __shared__ _Float16 lds[16384];             // 32 KB: Ah|Al|Bh|Bl, each [128][32]
    _Float16* Ahs = lds;
    _Float16* Als = lds + 4096;
    _Float16* Bhs = lds + 8192;
    _Float16* Bls = lds + 12288;

    // bijective XCD swizzle (nwg=1875): q8=234, r8=3
    const int bid = blockIdx.x;
    const int q8 = 1875 / 8, r8 = 1875 % 8;
    const int xcd = bid & 7, wi = bid >> 3;
    const int wg = (xcd < r8 ? xcd * (q8 + 1) : r8 * (q8 + 1) + (xcd - r8) * q8) + wi;
    const int bm = wg / 5, bn = wg % 5;

    const int tid = threadIdx.x;
    const int wid = tid >> 6, lane = tid & 63;
    const int fr = lane & 15, fq = lane >> 4;
    const int wm = (wid >> 1) * 64, wn = (wid & 1) * 64;

    const float*     Ag  = X  + (size_t)(bm * 128) * KDIM;
    const _Float16*  Bhg = Wh + (size_t)(bn * 128) * KDIM;
    const _Float16*  Blg = Wl + (size_t)(bn * 128) * KDIM;

    f32x4 acc[4][4];
    #pragma unroll
    for (int i = 0; i < 4; ++i)
        #pragma unroll
        for (int j = 0; j < 4; ++j)
            acc[i][j] = (f32x4){0.f, 0.f, 0.f, 0.f};

    for (int kk = 0; kk < 16; ++kk) {
        const int kh = kk * 32;
        #pragma unroll
        for (int q = 0; q < 2; ++q) {
            const int c = wid * 2 + q;
            const int srow = lane >> 2, sc8 = (lane & 3) * 8;
            const size_t go = (size_t)(c * 16 + srow) * KDIM + kh + sc8;
            GLD16(Bhg + go, Bhs + c * 512);
            GLD16(Blg + go, Bls + c * 512);
        }
        #pragma unroll
        for (int c = 0; c < 2; ++c) {
            const int idx8 = c * 256 + tid;
            const int row = idx8 >> 2, k8 = (idx8 & 3) * 8;
            const float4* xp = (const float4*)(Ag + (size_t)row * KDIM + kh + k8);
            float4 v0 = xp[0], v1 = xp[1];
            float xs[8] = {v0.x, v0.y, v0.z, v0.w, v1.x, v1.y, v1.z, v1.w};
            f16x8 h, l;
            #pragma unroll
            for (int q = 0; q < 8; ++q) {
                _Float16 hh = (_Float16)xs[q];
                h[q] = hh;
                l[q] = (_Float16)(xs[q] - (float)hh);
            }
            *(f16x8*)&Ahs[row * 32 + k8] = h;
            *(f16x8*)&Als[row * 32 + k8] = l;
        }
        __syncthreads();

        f16x8 ah[4], al[4], bh[4], bl[4];
        #pragma unroll
        for (int i = 0; i < 4; ++i) {
            const int ro = (wm + i * 16 + fr) * 32 + fq * 8;
            ah[i] = *(const f16x8*)&Ahs[ro];
            al[i] = *(const f16x8*)&Als[ro];
            const int co = (wn + i * 16 + fr) * 32 + fq * 8;
            bh[i] = *(const f16x8*)&Bhs[co];
            bl[i] = *(const f16x8*)&Bls[co];
        }
        #pragma unroll
        for (int i = 0; i < 4; ++i)
            #pragma unroll
            for (int j = 0; j < 4; ++j) {
                acc[i][j] = __builtin_amdgcn_mfma_f32_16x16x32_f16(ah[i], bh[j], acc[i][j], 0, 0, 0);
                acc[i][j] = __builtin_amdgcn_mfma_f32_16x16x32_f16(ah[i], bl[j], acc[i][j], 0, 0, 0);
                acc[i][j] = __builtin_amdgcn_mfma_f32_16x16x32_f16(al[i], bh[j], acc[i][j], 0, 0, 0);
            }
        __syncthreads();
    }

    float* cb = out + CB_OFF;
    // C-write: col = lane&15, row = (lane>>4)*4 + reg   [m89-verified]
    #pragma unroll
    for (int i = 0; i < 4; ++i) {
        #pragma unroll
        for (int r = 0; r < 4; ++r) {
            const int m = bm * 128 + wm + i * 16 + fq * 4 + r;
            float* orow = cb + (size_t)m * GE + bn * 128 + wn;
            #pragma unroll
            for (int j = 0; j < 4; ++j)
                orow[j * 16 + fr] = acc[i][j][r] + bvec[bn * 128 + wn + j * 16 + fr];
        }
    }

    // ---------------- ownership handoff -----------------------------------
    __syncthreads();                       // drain all threads' stores (vmcnt 0)
    float*    s_avgp = (float*)lds;                  // 2560 B
    unsigned* s_cnt  = (unsigned*)((char*)lds + 2560);
    unsigned* s_own  = (unsigned*)((char*)lds + 5120); // [4]
    for (int i = tid; i < GE; i += 256) { s_avgp[i] = 0.f; s_cnt[i] = 0u; }
    if (tid < 4) {
        __threadfence();                   // agent-scope release of our tile
        unsigned old = __hip_atomic_fetch_add(&panelcnt[bm * 4 + tid], 1u,
                                              __ATOMIC_ACQ_REL,
                                              __HIP_MEMORY_SCOPE_AGENT);
        unsigned o = (old == 4u) ? 1u : 0u;
        if (o) __threadfence();            // acquire: invalidate stale lines
        s_own[tid] = o;
    }
    __syncthreads();

    const bool anyown = (s_own[0] | s_own[1] | s_own[2] | s_own[3]) != 0u;
    if (anyown) {
        const int h2 = lane >> 5, il = lane & 31;
        float accp[10];
        #pragma unroll
        for (int i = 0; i < 10; ++i) accp[i] = 0.f;

        for (int sp = 0; sp < 4; ++sp) {
            if (!s_own[sp]) continue;      // uniform per block
            for (int rr = 0; rr < 8; ++rr) {
                const int n = bm * 128 + sp * 32 + wid * 8 + rr;
                float* Lrow = cb + (size_t)n * GE + h2 * NE;
                const float* Urow = gumbel + (size_t)(2 * n + h2) * NE;

                float lg[10], zg[10];
                #pragma unroll
                for (int i = 0; i < 10; ++i) {
                    int e = il + 32 * i;
                    lg[i] = Lrow[e];
                    float gn = -logf(-logf(Urow[e] + 1e-10f) + 1e-10f);
                    zg[i] = lg[i] + gn;
                }

                float pv1, pv2; int pi1, pi2;
                top2_half(lg, il, pv1, pi1, pv2, pi2);
                float gv1, gv2; int gi1, gi2;
                top2_half(zg, il, gv1, gi1, gv2, gi2);

                int k_plain = pi1;
                if (pv1 - pv2 < MARGIN)
                    k_plain = resolve2(X, Wf, bvec, Urow, n, h2, pi1, pi2, false, il);
                int k_g = gi1;
                if (gv1 - gv2 < MARGIN)
                    k_g = resolve2(X, Wf, bvec, Urow, n, h2, gi1, gi2, true, il);

                float s = 0.f, ex[10];
                #pragma unroll
                for (int i = 0; i < 10; ++i) { ex[i] = expf(lg[i] - pv1); s += ex[i]; }
                #pragma unroll
                for (int m = 1; m <= 16; m <<= 1) s += __shfl_xor(s, m);
                float inv = 1.f / s;
                #pragma unroll
                for (int i = 0; i < 10; ++i) accp[i] += ex[i] * inv;

                if (il == 0) atomicAdd(&s_cnt[h2 * NE + k_plain], 1u);

                #pragma unroll
                for (int i = 0; i < 10; ++i) {
                    int e = il + 32 * i;
                    Lrow[e] = (e == k_g) ? 1.f : 0.f;
                }
                const float* ent = entries + (size_t)(h2 * NE + k_g) * DDIM;
                float* qrow = out + (size_t)n * ODIM + h2 * DDIM;
                #pragma unroll
                for (int j = 0; j < 12; ++j) {
                    int d = il + 32 * j;
                    qrow[d] = ent[d];
                }
            }
        }

        #pragma unroll
        for (int i = 0; i < 10; ++i)
            atomicAdd(&s_avgp[h2 * NE + il + 32 * i], accp[i]);
        __syncthreads();
        for (int i = tid; i < GE; i += 256) {
            float a = s_avgp[i];
            if (a != 0.f) atomicAdd(&gavgp[i], a);
            unsigned c = s_cnt[i];
            if (c) atomicAdd(&gcnt[i], c);
        }
    }
}

// ---------------- Kernel C: perplexity scalars ----------------------------
__global__ void finalize_kernel(const float* __restrict__ gavgp,
                                const unsigned int* __restrict__ gcnt,
                                float* __restrict__ out)
{
    __shared__ double sc[GE], sp[GE];
    const int t = threadIdx.x;
    if (t < GE) {
        double hp = (double)gcnt[t] * (1.0 / 48000.0);
        sc[t] = hp * log(hp + 1e-7);
        double ap = (double)gavgp[t] * (1.0 / 48000.0);
        sp[t] = ap * log(ap + 1e-7);
    }
    __syncthreads();
    if (t == 0) {
        double c0 = 0, c1 = 0, p0 = 0, p1 = 0;
        for (int e = 0; e < NE; ++e) { c0 += sc[e]; p0 += sp[e]; }
        for (int e = NE; e < GE; ++e) { c1 += sc[e]; p1 += sp[e]; }
        out[SC_OFF]     = (float)(exp(-c0) + exp(-c1));
        out[SC_OFF + 1] = (float)(exp(-p0) + exp(-p1));
    }
}

// ---------------- launch --------------------------------------------------
extern "C" void kernel_launch(void* const* d_in, const int* in_sizes, int n_in,
                              void* d_out, int out_size, void* d_ws, size_t ws_size,
                              hipStream_t stream)
{
    const float* X       = (const float*)d_in[0];
    const float* Wf      = (const float*)d_in[1];
    const float* bvec    = (const float*)d_in[2];
    const float* entries = (const float*)d_in[3];
    const float* gumbel  = (const float*)d_in[4];
    float* out = (float*)d_out;

    float* gavgp = (float*)d_ws;                                   // 2560 B
    unsigned int* gcnt = (unsigned int*)((char*)d_ws + 2560);      // 2560 B
    unsigned int* panelcnt = (unsigned int*)((char*)d_ws + 5120);  // 1500*4 B
    _Float16* Wh = (_Float16*)((char*)d_ws + 11264);               // 640 KB
    _Float16* Wl = (_Float16*)((char*)d_ws + 11264 + 655360);      // 640 KB

    hipMemsetAsync(d_ws, 0, 11264, stream);
    split16<<<160, 256, 0, stream>>>(Wf, Wh, Wl, 40960);           // 640*512/8
    gemm_fused<<<1875, 256, 0, stream>>>(X, Wf, Wh, Wl, bvec, entries,
                                         gumbel, out, gavgp, gcnt, panelcnt);
    finalize_kernel<<<1, 640, 0, stream>>>(gavgp, gcnt, out);
}

// Round 7
// 316.063 us; speedup vs baseline: 2.1847x; 2.1847x over previous
//
#include <hip/hip_runtime.h>
#include <math.h>
#include <stdint.h>

#define NROWS 48000
#define KDIM 512
#define NE 320
#define GE 640
#define DDIM 384
#define ODIM 768
#define CB_OFF 36864000ul
#define SC_OFF 67584000ul
#define MARGIN 4e-3f

using f16x8 = __attribute__((ext_vector_type(8))) _Float16;
using f32x4 = __attribute__((ext_vector_type(4))) float;

#define GLD16(gp, lp)                                                          \
    __builtin_amdgcn_global_load_lds(                                          \
        (const __attribute__((address_space(1))) uint32_t*)(gp),               \
        (__attribute__((address_space(3))) uint32_t*)(lp), 16, 0, 0)

// ---------------- split f32 -> f16 hi + f16 lo (W only, 1.3 MB) -----------
__global__ __launch_bounds__(256) void split16(const float* __restrict__ src,
                                               _Float16* __restrict__ hi,
                                               _Float16* __restrict__ lo,
                                               int n8)
{
    int i = blockIdx.x * 256 + threadIdx.x;
    if (i >= n8) return;
    float4 v0 = *((const float4*)src + 2 * (size_t)i);
    float4 v1 = *((const float4*)src + 2 * (size_t)i + 1);
    float x[8] = {v0.x, v0.y, v0.z, v0.w, v1.x, v1.y, v1.z, v1.w};
    f16x8 h, l;
    #pragma unroll
    for (int k = 0; k < 8; ++k) {
        _Float16 hh = (_Float16)x[k];
        h[k] = hh;
        l[k] = (_Float16)(x[k] - (float)hh);
    }
    *(f16x8*)(hi + (size_t)i * 8) = h;
    *(f16x8*)(lo + (size_t)i * 8) = l;
}

// ---------------- Kernel A: logits = X @ W^T + b (round-5 proven) ---------
__global__ __launch_bounds__(256) void gemm_cvt(
    const float* __restrict__ X,
    const _Float16* __restrict__ Wh, const _Float16* __restrict__ Wl,
    const float* __restrict__ bvec, float* __restrict__ Lout)
{
    __shared__ _Float16 lds[16384];             // 32 KB: Ah|Al|Bh|Bl, each [128][32]
    _Float16* Ahs = lds;
    _Float16* Als = lds + 4096;
    _Float16* Bhs = lds + 8192;
    _Float16* Bls = lds + 12288;

    // bijective XCD swizzle (nwg=1875): q8=234, r8=3
    const int bid = blockIdx.x;
    const int q8 = 1875 / 8, r8 = 1875 % 8;
    const int xcd = bid & 7, wi = bid >> 3;
    const int wg = (xcd < r8 ? xcd * (q8 + 1) : r8 * (q8 + 1) + (xcd - r8) * q8) + wi;
    const int bm = wg / 5, bn = wg % 5;

    const int tid = threadIdx.x;
    const int wid = tid >> 6, lane = tid & 63;
    const int fr = lane & 15, fq = lane >> 4;
    const int wm = (wid >> 1) * 64, wn = (wid & 1) * 64;

    const float*     Ag  = X  + (size_t)(bm * 128) * KDIM;
    const _Float16*  Bhg = Wh + (size_t)(bn * 128) * KDIM;
    const _Float16*  Blg = Wl + (size_t)(bn * 128) * KDIM;

    f32x4 acc[4][4];
    #pragma unroll
    for (int i = 0; i < 4; ++i)
        #pragma unroll
        for (int j = 0; j < 4; ++j)
            acc[i][j] = (f32x4){0.f, 0.f, 0.f, 0.f};

    for (int kk = 0; kk < 16; ++kk) {
        const int kh = kk * 32;
        #pragma unroll
        for (int q = 0; q < 2; ++q) {
            const int c = wid * 2 + q;
            const int srow = lane >> 2, sc8 = (lane & 3) * 8;
            const size_t go = (size_t)(c * 16 + srow) * KDIM + kh + sc8;
            GLD16(Bhg + go, Bhs + c * 512);
            GLD16(Blg + go, Bls + c * 512);
        }
        #pragma unroll
        for (int c = 0; c < 2; ++c) {
            const int idx8 = c * 256 + tid;
            const int row = idx8 >> 2, k8 = (idx8 & 3) * 8;
            const float4* xp = (const float4*)(Ag + (size_t)row * KDIM + kh + k8);
            float4 v0 = xp[0], v1 = xp[1];
            float xs[8] = {v0.x, v0.y, v0.z, v0.w, v1.x, v1.y, v1.z, v1.w};
            f16x8 h, l;
            #pragma unroll
            for (int q = 0; q < 8; ++q) {
                _Float16 hh = (_Float16)xs[q];
                h[q] = hh;
                l[q] = (_Float16)(xs[q] - (float)hh);
            }
            *(f16x8*)&Ahs[row * 32 + k8] = h;
            *(f16x8*)&Als[row * 32 + k8] = l;
        }
        __syncthreads();

        f16x8 ah[4], al[4], bh[4], bl[4];
        #pragma unroll
        for (int i = 0; i < 4; ++i) {
            const int ro = (wm + i * 16 + fr) * 32 + fq * 8;
            ah[i] = *(const f16x8*)&Ahs[ro];
            al[i] = *(const f16x8*)&Als[ro];
            const int co = (wn + i * 16 + fr) * 32 + fq * 8;
            bh[i] = *(const f16x8*)&Bhs[co];
            bl[i] = *(const f16x8*)&Bls[co];
        }
        #pragma unroll
        for (int i = 0; i < 4; ++i)
            #pragma unroll
            for (int j = 0; j < 4; ++j) {
                acc[i][j] = __builtin_amdgcn_mfma_f32_16x16x32_f16(ah[i], bh[j], acc[i][j], 0, 0, 0);
                acc[i][j] = __builtin_amdgcn_mfma_f32_16x16x32_f16(ah[i], bl[j], acc[i][j], 0, 0, 0);
                acc[i][j] = __builtin_amdgcn_mfma_f32_16x16x32_f16(al[i], bh[j], acc[i][j], 0, 0, 0);
            }
        __syncthreads();
    }

    // C/D layout: col = lane&15, row = (lane>>4)*4 + reg   [m89-verified]
    #pragma unroll
    for (int i = 0; i < 4; ++i) {
        #pragma unroll
        for (int r = 0; r < 4; ++r) {
            const int m = bm * 128 + wm + i * 16 + fq * 4 + r;
            float* orow = Lout + (size_t)m * GE + bn * 128 + wn;
            #pragma unroll
            for (int j = 0; j < 4; ++j) {
                const int n = bn * 128 + wn + j * 16 + fr;
                orow[j * 16 + fr] = acc[i][j][r] + bvec[n];
            }
        }
    }
}

// ---------------- helpers -------------------------------------------------
__device__ __forceinline__ bool better(float a, int ia, float b, int ib) {
    return (a > b) || (a == b && ia < ib);
}

__device__ __forceinline__ void t2merge(float& v1, int& i1, float& v2, int& i2,
                                        float ov1, int oi1, float ov2, int oi2)
{
    if (better(ov1, oi1, v1, i1)) {
        float tv = v1; int ti = i1;
        v1 = ov1; i1 = oi1;
        if (better(ov2, oi2, tv, ti)) { v2 = ov2; i2 = oi2; }
        else                          { v2 = tv;  i2 = ti;  }
    } else if (better(ov1, oi1, v2, i2)) {
        v2 = ov1; i2 = oi1;
    }
}

// top-2 butterfly within a 16-lane quarter-wave
__device__ __forceinline__ void bfly16(float& v1, int& i1, float& v2, int& i2)
{
    #pragma unroll
    for (int m = 1; m <= 8; m <<= 1) {
        float ov1 = __shfl_xor(v1, m); int oi1 = __shfl_xor(i1, m);
        float ov2 = __shfl_xor(v2, m); int oi2 = __shfl_xor(i2, m);
        t2merge(v1, i1, v2, i2, ov1, oi1, ov2, oi2);
    }
}

// fp64 re-resolution of a near-tied argmax within a 16-lane quarter-wave
__device__ int resolve16(const float* __restrict__ X, const float* __restrict__ W,
                         const float* __restrict__ bvec, const float* __restrict__ Urow,
                         int n, int cb, int c1, int c2, bool gum, int l)
{
    const float* xr = X + (size_t)n * KDIM;
    const float* w1 = W + (size_t)(cb * NE + c1) * KDIM;
    const float* w2 = W + (size_t)(cb * NE + c2) * KDIM;
    double d1 = 0.0, d2 = 0.0;
    #pragma unroll
    for (int j = 0; j < 32; ++j) {
        int k = l + 16 * j;
        double xv = (double)xr[k];
        d1 += xv * (double)w1[k];
        d2 += xv * (double)w2[k];
    }
    #pragma unroll
    for (int m = 1; m <= 8; m <<= 1) {
        d1 += __shfl_xor(d1, m);
        d2 += __shfl_xor(d2, m);
    }
    d1 += (double)bvec[cb * NE + c1];
    d2 += (double)bvec[cb * NE + c2];
    if (gum) {
        d1 += -log(-log((double)Urow[c1] + 1e-10) + 1e-10);
        d2 += -log(-log((double)Urow[c2] + 1e-10) + 1e-10);
    }
    return (d2 > d1 || (d2 == d1 && c2 < c1)) ? c2 : c1;
}

// ---------------- Kernel B: vectorized per-row epilogue -------------------
// Quarter-wave (16 lanes) owns one (row, codebook): float4 loads/stores,
// lane l covers cols l*4 + q*64 + c (q=0..4, c=0..3).
__global__ __launch_bounds__(256) void epilogue_kernel(
    const float* __restrict__ X, const float* __restrict__ W,
    const float* __restrict__ bvec, const float* __restrict__ entries,
    const float* __restrict__ gumbel, float* __restrict__ out,
    float* __restrict__ gavgp, unsigned int* __restrict__ gcnt)
{
    __shared__ float s_avgp[GE];
    __shared__ unsigned int s_cnt[GE];
    const int tid = threadIdx.x;
    for (int i = tid; i < GE; i += 256) { s_avgp[i] = 0.f; s_cnt[i] = 0u; }
    __syncthreads();

    const int wid = tid >> 6, lane = tid & 63;
    const int qw = lane >> 4, l = lane & 15;
    const int cb = qw & 1, rsub = qw >> 1;

    float accp[20];
    #pragma unroll
    for (int t = 0; t < 20; ++t) accp[t] = 0.f;

    for (int rr = 0; rr < 8; ++rr) {
        const int n = blockIdx.x * 64 + wid * 16 + rr * 2 + rsub;
        float* Lrow = out + CB_OFF + (size_t)n * GE + cb * NE;
        const float* Urow = gumbel + (size_t)(2 * n + cb) * NE;

        float lg[20];
        float v1 = -3.4e38f, v2 = -3.4e38f; int i1 = 0x7fffffff, i2 = 0x7fffffff;
        float g1 = -3.4e38f, g2 = -3.4e38f; int gi1 = 0x7fffffff, gi2 = 0x7fffffff;
        #pragma unroll
        for (int q = 0; q < 5; ++q) {
            float4 lv = *(const float4*)(Lrow + l * 4 + q * 64);
            float4 uv = *(const float4*)(Urow + l * 4 + q * 64);
            float lx[4] = {lv.x, lv.y, lv.z, lv.w};
            float ux[4] = {uv.x, uv.y, uv.z, uv.w};
            #pragma unroll
            for (int c = 0; c < 4; ++c) {
                float x = lx[c];
                lg[q * 4 + c] = x;
                int e = l * 4 + q * 64 + c;
                if (better(x, e, v1, i1)) { v2 = v1; i2 = i1; v1 = x; i1 = e; }
                else if (better(x, e, v2, i2)) { v2 = x; i2 = e; }
                float z = x + (-logf(-logf(ux[c] + 1e-10f) + 1e-10f));
                if (better(z, e, g1, gi1)) { g2 = g1; gi2 = gi1; g1 = z; gi1 = e; }
                else if (better(z, e, g2, gi2)) { g2 = z; gi2 = e; }
            }
        }
        bfly16(v1, i1, v2, i2);
        bfly16(g1, gi1, g2, gi2);

        int k_plain = i1;
        if (v1 - v2 < MARGIN)
            k_plain = resolve16(X, W, bvec, Urow, n, cb, i1, i2, false, l);
        int k_g = gi1;
        if (g1 - g2 < MARGIN)
            k_g = resolve16(X, W, bvec, Urow, n, cb, gi1, gi2, true, l);

        // softmax over the 320 entries of this (row, codebook)
        float s = 0.f, ex[20];
        #pragma unroll
        for (int t = 0; t < 20; ++t) { ex[t] = expf(lg[t] - v1); s += ex[t]; }
        #pragma unroll
        for (int m = 1; m <= 8; m <<= 1) s += __shfl_xor(s, m);
        float inv = 1.f / s;
        #pragma unroll
        for (int t = 0; t < 20; ++t) accp[t] += ex[t] * inv;

        if (l == 0) atomicAdd(&s_cnt[cb * NE + k_plain], 1u);

        // one-hot cb write (float4)
        #pragma unroll
        for (int q = 0; q < 5; ++q) {
            const int c0 = l * 4 + q * 64;
            float4 v;
            v.x = (c0     == k_g) ? 1.f : 0.f;
            v.y = (c0 + 1 == k_g) ? 1.f : 0.f;
            v.z = (c0 + 2 == k_g) ? 1.f : 0.f;
            v.w = (c0 + 3 == k_g) ? 1.f : 0.f;
            *(float4*)(Lrow + c0) = v;
        }
        // quantized gather (float4, 6 per lane)
        const float4* ent = (const float4*)(entries + (size_t)(cb * NE + k_g) * DDIM);
        float4* qrow = (float4*)(out + (size_t)n * ODIM + cb * DDIM);
        #pragma unroll
        for (int t = 0; t < 6; ++t) qrow[l + t * 16] = ent[l + t * 16];
    }

    #pragma unroll
    for (int q = 0; q < 5; ++q)
        #pragma unroll
        for (int c = 0; c < 4; ++c)
            atomicAdd(&s_avgp[cb * NE + l * 4 + q * 64 + c], accp[q * 4 + c]);
    __syncthreads();
    for (int i = tid; i < GE; i += 256) {
        atomicAdd(&gavgp[i], s_avgp[i]);
        unsigned int c = s_cnt[i];
        if (c) atomicAdd(&gcnt[i], c);
    }
}

// ---------------- Kernel C: perplexity scalars ----------------------------
__global__ void finalize_kernel(const float* __restrict__ gavgp,
                                const unsigned int* __restrict__ gcnt,
                                float* __restrict__ out)
{
    __shared__ double sc[GE], sp[GE];
    const int t = threadIdx.x;
    if (t < GE) {
        double hp = (double)gcnt[t] * (1.0 / 48000.0);
        sc[t] = hp * log(hp + 1e-7);
        double ap = (double)gavgp[t] * (1.0 / 48000.0);
        sp[t] = ap * log(ap + 1e-7);
    }
    __syncthreads();
    if (t == 0) {
        double c0 = 0, c1 = 0, p0 = 0, p1 = 0;
        for (int e = 0; e < NE; ++e) { c0 += sc[e]; p0 += sp[e]; }
        for (int e = NE; e < GE; ++e) { c1 += sc[e]; p1 += sp[e]; }
        out[SC_OFF]     = (float)(exp(-c0) + exp(-c1));
        out[SC_OFF + 1] = (float)(exp(-p0) + exp(-p1));
    }
}

// ---------------- launch --------------------------------------------------
extern "C" void kernel_launch(void* const* d_in, const int* in_sizes, int n_in,
                              void* d_out, int out_size, void* d_ws, size_t ws_size,
                              hipStream_t stream)
{
    const float* X       = (const float*)d_in[0];
    const float* Wf      = (const float*)d_in[1];
    const float* bvec    = (const float*)d_in[2];
    const float* entries = (const float*)d_in[3];
    const float* gumbel  = (const float*)d_in[4];
    float* out = (float*)d_out;

    float* gavgp = (float*)d_ws;                                   // 2560 B
    unsigned int* gcnt = (unsigned int*)((char*)d_ws + 2560);      // 2560 B
    _Float16* Wh = (_Float16*)((char*)d_ws + 8192);                // 640 KB
    _Float16* Wl = (_Float16*)((char*)d_ws + 8192 + 655360);       // 640 KB

    hipMemsetAsync(d_ws, 0, 8192, stream);
    split16<<<160, 256, 0, stream>>>(Wf, Wh, Wl, 40960);           // 640*512/8
    gemm_cvt<<<1875, 256, 0, stream>>>(X, Wh, Wl, bvec, out + CB_OFF);
    epilogue_kernel<<<750, 256, 0, stream>>>(X, Wf, bvec, entries, gumbel, out, gavgp, gcnt);
    finalize_kernel<<<1, 640, 0, stream>>>(gavgp, gcnt, out);
}